// Round 10
// baseline (569.372 us; speedup 1.0000x reference)
//
#include <hip/hip_runtime.h>

// Fused StyleGAN2 conv_downsample_2d, f32-VALU, pipelined + 2-blocks/CU.
//   out[n,oc,oh,ow] = sum_c w[c,oc] * y[n,c,2oh,2ow]
//   y = separable FIR {1,3,3,1}/8 (vert) x {1,3,3,1}/8 (horiz), pad=1
//
// Design ledger:
//  - bf16 MFMA: ~3.6% per-term noise on this op (r2/3/5) -> fails threshold.
//  - NEVER pass __launch_bounds__ min-waves arg (r6/r8 spilled).
//  - r9: acc 8x8 + xr[20] -> ~192 total regs -> 1 block/CU (22.5% occ),
//    VALU 35% (barrier/latency holes, nothing to overlap). This round:
//    acc 8x4 = 32 regs + xr[11] + precomputed staging addrs -> <=128 total
//    -> 2 independent 512-thr blocks/CU overlap each other's stalls.
//  - Keep r9's reg-prefetch (T14), 2 barriers/chunk, w from L1, raw-x stage.
//
// Block: 512 thr; tile = 256 oc x (8 oh x 8 ow); K-chunks of 16 ch.
// Grid (32, 32, 4). Patch 18x18 per channel; 324*16 = 5184 pts / 512 thr.

#define CH    16
#define PWP   19               // x_s row pitch (odd)
#define CSTR  (18 * PWP + 1)   // 343 floats per channel (odd)
#define YPIT  68               // y_s per-channel pitch (64 sp + 4)
#define NPTS  (CH * 324)       // 5184

typedef __attribute__((ext_vector_type(4))) float f32x4;

__global__ __launch_bounds__(512)
void fused_downconv_f32v5(const float* __restrict__ x, const float* __restrict__ w,
                          float* __restrict__ out) {
    __shared__ __align__(16) float x_s[CH * CSTR];   // 21952 B
    __shared__ __align__(16) float y_s[CH * YPIT];   //  4352 B  (26.3 KB)

    const int tid  = threadIdx.x;
    const int oc_g = tid >> 4;    // 0..31 -> oc block of 8
    const int sp_g = tid & 15;    // 0..15 -> sp block of 4

    const int ow0 = blockIdx.x * 8;
    const int oh0 = blockIdx.y * 8;
    const int n   = blockIdx.z;

    const int rbase = 2 * oh0 - 1;
    const int cbase = 2 * ow0 - 1;

    // ---- precompute staging maps (c0-invariant): 11 pts/thread ----
    int   goff[11];    // cc*262144 + gr*512 + gc
    int   laddr[11];   // cc*CSTR + row*PWP + col
    unsigned ldmask = 0;   // bit k: global load valid (in-bounds)
    unsigned stmask = 0;   // bit k: point exists (idx < NPTS)
    {
        #pragma unroll
        for (int k = 0; k < 11; k++) {
            int idx = tid + 512 * k;
            bool have = (idx < NPTS);
            int ccl = idx / 324;
            int rem = idx - ccl * 324;
            int row = rem / 18;
            int col = rem - row * 18;
            laddr[k] = ccl * CSTR + row * PWP + col;
            int gr = rbase + row, gc = cbase + col;
            bool ok = have && ((unsigned)gr < 512u) && ((unsigned)gc < 512u);
            goff[k] = ok ? (ccl * 262144 + gr * 512 + gc) : 0;
            if (ok)   ldmask |= (1u << k);
            if (have) stmask |= (1u << k);
        }
    }

    // y-phase mapping: 2 adjacent-ow outputs per thread
    const int yc_cc  = tid >> 5;         // 0..15
    const int yc_ohl = (tid & 31) >> 2;  // 0..7
    const int yc_owp = tid & 3;          // 0..3 -> owl = 2*owp, 2*owp+1

    float xr[11];
    f32x4 acc4[8];
    #pragma unroll
    for (int i = 0; i < 8; i++) acc4[i] = (f32x4){0.f, 0.f, 0.f, 0.f};

    auto do_prefetch = [&](int c0) {
        const float* xb = x + ((size_t)(n * 128 + c0)) * 262144;
        #pragma unroll
        for (int k = 0; k < 11; k++)
            xr[k] = ((ldmask >> k) & 1u) ? xb[goff[k]] : 0.f;
    };

    do_prefetch(0);

    for (int c0 = 0; c0 < 128; c0 += CH) {
        // ---- write phase: xr -> x_s ----
        #pragma unroll
        for (int k = 0; k < 11; k++)
            if ((stmask >> k) & 1u) x_s[laddr[k]] = xr[k];
        __syncthreads();   // x_s ready (also fences prev GEMM y_s reads)

        // ---- prefetch next chunk; latency hides under y + GEMM ----
        if (c0 + CH < 128) do_prefetch(c0 + CH);

        // ---- y phase: separable FIR; 2 y per thread ----
        {
            const float* xb = &x_s[yc_cc * CSTR + (2 * yc_ohl) * PWP + 4 * yc_owp];
            float colv[6];
            #pragma unroll
            for (int j = 0; j < 6; j++)
                colv[j] = 0.125f * (xb[j] + xb[3 * PWP + j])
                        + 0.375f * (xb[PWP + j] + xb[2 * PWP + j]);
            float y0 = 0.125f * (colv[0] + colv[3]) + 0.375f * (colv[1] + colv[2]);
            float y1 = 0.125f * (colv[2] + colv[5]) + 0.375f * (colv[3] + colv[4]);
            *(float2*)&y_s[yc_cc * YPIT + yc_ohl * 8 + 2 * yc_owp] = make_float2(y0, y1);
        }
        __syncthreads();   // y_s ready

        // ---- GEMM: 8 oc x 4 sp per thread; w from L1, y from LDS ----
        {
            const float* wp = w + (size_t)c0 * 256 + oc_g * 8;
            #pragma unroll 4
            for (int cc = 0; cc < CH; cc++) {
                f32x4 y4 = *(const f32x4*)&y_s[cc * YPIT + sp_g * 4];
                f32x4 wa = *(const f32x4*)&wp[cc * 256];
                f32x4 wb = *(const f32x4*)&wp[cc * 256 + 4];
                acc4[0] += wa.x * y4;
                acc4[1] += wa.y * y4;
                acc4[2] += wa.z * y4;
                acc4[3] += wa.w * y4;
                acc4[4] += wb.x * y4;
                acc4[5] += wb.y * y4;
                acc4[6] += wb.z * y4;
                acc4[7] += wb.w * y4;
            }
        }
        // no 3rd barrier: next x_s write is fenced by barrier 1; y_s reads
        // drain at that barrier's lgkmcnt(0) before y_s is rewritten.
    }

    // ---- epilogue: sp = sp_g*4 + j -> oh_l = sp_g>>1, ow = (sp_g&1)*4 + j ----
    {
        const int oh_l = sp_g >> 1;
        const int ow4  = (sp_g & 1) * 4;
        const size_t base = (((size_t)n * 256 + (size_t)oc_g * 8) * 256
                             + (size_t)(oh0 + oh_l)) * 256 + ow0 + ow4;
        #pragma unroll
        for (int i = 0; i < 8; i++)
            *(f32x4*)&out[base + (size_t)i * 65536] = acc4[i];
    }
}

extern "C" void kernel_launch(void* const* d_in, const int* in_sizes, int n_in,
                              void* d_out, int out_size, void* d_ws, size_t ws_size,
                              hipStream_t stream) {
    const float* x = (const float*)d_in[0];
    const float* w = (const float*)d_in[1];
    float* out = (float*)d_out;

    dim3 grid(32, 32, 4);   // ow-tiles(8), oh-tiles(8), n
    dim3 block(512);
    hipLaunchKernelGGL(fused_downconv_f32v5, grid, block, 0, stream, x, w, out);
}

// Round 11
// 430.141 us; speedup vs baseline: 1.3237x; 1.3237x over previous
//
#include <hip/hip_runtime.h>

// Fused StyleGAN2 conv_downsample_2d, f32-VALU, pipelined, register-trimmed.
//   out[n,oc,oh,ow] = sum_c w[c,oc] * y[n,c,2oh,2ow]
//   y = separable FIR {1,3,3,1}/8 (vert) x {1,3,3,1}/8 (horiz), pad=1
//
// Design ledger:
//  - bf16 MFMA: precision-independent ~0.7 absmax on this op (r2/3/5) -> f32.
//  - NEVER pass __launch_bounds__ min-waves arg (r6/r8 spilled to scratch).
//  - Occupancy is NOT the binding constraint (r8 87% slow, r10 44% slow);
//    FMA-per-byte density is: keep 8x8 acc + 8oh x 16ow tile (r9/r10 lesson:
//    8-wide tiles waste 64B sectors, +36% FETCH).
//  - r9 limiter: VGPR 128 (acc 64 + xr[20]) -> 1 block/CU, stalls exposed.
//    This round: CH=8 -> xr[10]; staging offsets PRECOMPUTED (c0-invariant)
//    -> target ~105 regs -> 2 blocks/CU to cross-hide barrier drains.
//  - Keep: T14 reg-prefetch, 2 barriers/chunk, w via L1, swizzled y_s.
//
// Block 512 thr; tile 256 oc x (8 oh x 16 ow); 16 K-chunks of 8 channels.
// Staging: wave wv stages channel (c0+wv): lane walks j = lane+64k over the
// 18x34 patch (row = j/34, col = j%34), k = 0..9 (j<612; k=9 only lane<36).

#define CH    8
#define RPIT  35               // x_s row pitch (floats)
#define CSTR  631              // x_s channel stride (18*35+1, odd)
#define YPIT  144              // y_s channel pitch (swizzled, max 139)

typedef __attribute__((ext_vector_type(4))) float f32x4;

__device__ __forceinline__ int yoff(int g) { return g * 8 + ((g >> 2) << 2); }

__global__ __launch_bounds__(512)
void fused_downconv_f32v6(const float* __restrict__ x, const float* __restrict__ w,
                          float* __restrict__ out) {
    __shared__ __align__(16) float x_s[CH * CSTR];   // 20192 B
    __shared__ __align__(16) float y_s[CH * YPIT];   //  4608 B  (24.2 KB)

    const int tid  = threadIdx.x;
    const int lane = tid & 63;
    const int wv   = tid >> 6;        // wave id = channel within chunk

    const int oc_g = tid >> 4;        // 0..31 -> oc block of 8
    const int sp_g = tid & 15;        // 0..15 -> sp block of 8

    const int ow0 = blockIdx.x * 16;
    const int oh0 = blockIdx.y * 8;
    const int n   = blockIdx.z;

    const int rbase = 2 * oh0 - 1;
    const int cbase = 2 * ow0 - 1;

    // ---- precompute staging walk (c0-invariant; bounds checks leave loop) ----
    int off[10];               // (rbase+row)*512 + (cbase+col), or 0 if masked
    unsigned ldmask = 0;       // bit k: global load valid
    unsigned wrapmask = 0;     // bit k: walk wraps at step k -> k+1
    int la0;                   // LDS write base (row0,col0 of this lane)
    {
        int row = (lane >= 34) ? 1 : 0;
        int col = lane - (row ? 34 : 0);
        la0 = wv * CSTR + row * RPIT + col;
        #pragma unroll
        for (int k = 0; k < 10; k++) {
            bool have = (k < 9) || (lane < 36);
            int gr = rbase + row, gc = cbase + col;
            bool ok = have && ((unsigned)gr < 512u) && ((unsigned)gc < 512u);
            off[k] = ok ? (gr * 512 + gc) : 0;
            if (ok) ldmask |= (1u << k);
            int c2 = col + 30;              // j += 64 : (+1 row, +30 col)
            bool wr = (c2 >= 34);
            if (wr) wrapmask |= (1u << k);
            col = wr ? (c2 - 34) : c2;
            row += wr ? 2 : 1;
        }
    }
    const unsigned stmask = (lane < 36) ? 0x3FFu : 0x1FFu;

    float xr[10];
    f32x4 accA[8], accB[8];    // 8 oc x (sp 0-3 / 4-7)
    #pragma unroll
    for (int i = 0; i < 8; i++) {
        accA[i] = (f32x4){0.f, 0.f, 0.f, 0.f};
        accB[i] = (f32x4){0.f, 0.f, 0.f, 0.f};
    }

    auto do_prefetch = [&](int c0) {
        const float* xb = x + ((size_t)(n * 128 + c0 + wv)) * 262144;
        #pragma unroll
        for (int k = 0; k < 10; k++)
            xr[k] = ((ldmask >> k) & 1u) ? xb[off[k]] : 0.f;
    };

    do_prefetch(0);

    // y-phase constants: lane -> ohl = lane>>3, owp = lane&7 (2 y per thread)
    const int yp_xb  = wv * CSTR + (lane >> 3) * (2 * RPIT) + (lane & 7) * 4;
    const int yp_sp  = (lane >> 3) * 16 + (lane & 7) * 2;
    const int yp_dst = wv * YPIT + yoff(yp_sp >> 3) + (yp_sp & 7);
    const int y_rd   = yoff(sp_g);

    for (int c0 = 0; c0 < 128; c0 += CH) {
        // ---- write phase: xr -> x_s ----
        {
            int la = la0;
            #pragma unroll
            for (int k = 0; k < 10; k++) {
                if ((stmask >> k) & 1u) x_s[la] = xr[k];
                la += ((wrapmask >> k) & 1u) ? 66 : 65;   // 35+30 or 70-4
            }
        }
        __syncthreads();   // x_s ready; prev GEMM y_s reads drained

        // ---- prefetch next chunk; latency hides under y + GEMM ----
        if (c0 + CH < 128) do_prefetch(c0 + CH);

        // ---- y phase: separable FIR; 2 y per thread ----
        {
            const float* xb = &x_s[yp_xb];
            float colv[6];
            #pragma unroll
            for (int j = 0; j < 6; j++)
                colv[j] = 0.125f * (xb[j] + xb[3 * RPIT + j])
                        + 0.375f * (xb[RPIT + j] + xb[2 * RPIT + j]);
            float y0 = 0.125f * (colv[0] + colv[3]) + 0.375f * (colv[1] + colv[2]);
            float y1 = 0.125f * (colv[2] + colv[5]) + 0.375f * (colv[3] + colv[4]);
            *(float2*)&y_s[yp_dst] = make_float2(y0, y1);
        }
        __syncthreads();   // y_s ready

        // ---- GEMM: 8 oc x 8 sp per thread; w from L1, y from LDS ----
        {
            const float* wp = w + (size_t)c0 * 256 + oc_g * 8;
            #pragma unroll
            for (int cc = 0; cc < CH; cc++) {
                f32x4 wa = *(const f32x4*)&wp[cc * 256];
                f32x4 wb = *(const f32x4*)&wp[cc * 256 + 4];
                f32x4 ya = *(const f32x4*)&y_s[cc * YPIT + y_rd];
                f32x4 yb = *(const f32x4*)&y_s[cc * YPIT + y_rd + 4];
                accA[0] += wa.x * ya;  accB[0] += wa.x * yb;
                accA[1] += wa.y * ya;  accB[1] += wa.y * yb;
                accA[2] += wa.z * ya;  accB[2] += wa.z * yb;
                accA[3] += wa.w * ya;  accB[3] += wa.w * yb;
                accA[4] += wb.x * ya;  accB[4] += wb.x * yb;
                accA[5] += wb.y * ya;  accB[5] += wb.y * yb;
                accA[6] += wb.z * ya;  accB[6] += wb.z * yb;
                accA[7] += wb.w * ya;  accB[7] += wb.w * yb;
            }
        }
        // no 3rd barrier: phases alternate RW targets; barrier1 fences x_s,
        // all GEMM y_s reads complete before any wave passes barrier1.
    }

    // ---- epilogue: sp = sp_g*8 + j -> oh_l = sp_g>>1, ow = (sp_g&1)*8 + j ----
    {
        const int oh_l = sp_g >> 1;
        const int owst = (sp_g & 1) * 8;
        const size_t obase = (((size_t)n * 256 + (size_t)oc_g * 8) * 256
                              + (size_t)(oh0 + oh_l)) * 256 + ow0 + owst;
        #pragma unroll
        for (int i = 0; i < 8; i++) {
            *(f32x4*)&out[obase + (size_t)i * 65536]     = accA[i];
            *(f32x4*)&out[obase + (size_t)i * 65536 + 4] = accB[i];
        }
    }
}

extern "C" void kernel_launch(void* const* d_in, const int* in_sizes, int n_in,
                              void* d_out, int out_size, void* d_ws, size_t ws_size,
                              hipStream_t stream) {
    const float* x = (const float*)d_in[0];
    const float* w = (const float*)d_in[1];
    float* out = (float*)d_out;

    dim3 grid(16, 32, 4);   // ow-tiles(16 wide), oh-tiles(8 tall), n
    dim3 block(512);
    hipLaunchKernelGGL(fused_downconv_f32v6, grid, block, 0, stream, x, w, out);
}

// Round 12
// 411.683 us; speedup vs baseline: 1.3830x; 1.0448x over previous
//
#include <hip/hip_runtime.h>

// Fused StyleGAN2 conv_downsample_2d, f32, register-FIR + SGPR-w GEMM.
//   out[n,oc,oh,ow] = sum_c w[c,oc] * y[n,c,2oh,2ow]
//   y = separable FIR {1,3,3,1}/8 (vert) x {1,3,3,1}/8 (horiz), pad=1
//
// Design ledger (r1-r11):
//  - bf16 MFMA: precision-independent ~0.7 absmax on this op -> f32 VALU.
//  - NEVER pass __launch_bounds__ min-waves arg (r6/r8 spilled).
//  - Occupancy alone doesn't fix stalls (r8/r10); LDS round-trips and
//    per-thread traffic do. r11 moved 2 LDS round trips per value; this
//    version moves ONE tiny v-tile: global->regs ->(vFIR in regs)-> v_s
//    (4.4 KB/chunk) -> GEMM computes y in-register (4 reads + 4 ops/cc)
//    and reads w via SGPR s_loads (readfirstlane'd wave-uniform base).
//  - 1 barrier/chunk, v_s double-buffered; loads(t+2) || vFIR(t+1) || GEMM(t).
//
// Block 512 thr = 8 waves. Tile: 256 oc x (4 oh x 16 ow). Wave = 32-oc strip,
// lane = one of 64 sp. K-chunks of 8 ch; wave wv stages channel c0+wv:
// lanes 0..33 own patch columns (10 rows x 34 cols), vertical FIR in regs.

#define VS 35   // v_s col pitch (odd -> 2-way max on GEMM reads)

__global__ __launch_bounds__(512)
void fused_downconv_v7(const float* __restrict__ x, const float* __restrict__ w,
                       float* __restrict__ out) {
    __shared__ __align__(16) float v_s[2 * 8 * 4 * VS];   // 8960 B

    const int tid  = threadIdx.x;
    const int lane = tid & 63;
    const int wv   = tid >> 6;   // wave id: staged channel offset, oc strip
    const int oc0  = __builtin_amdgcn_readfirstlane((tid >> 6) << 5);

    const int ow0 = blockIdx.x * 16;
    const int oh0 = blockIdx.y * 4;
    const int n   = blockIdx.z;

    const int rbase = 2 * oh0 - 1;
    const int cbase = 2 * ow0 - 1;

    // ---- staging map: lane<34 owns col cbase+lane, rows rbase..rbase+9 ----
    int off[10];
    unsigned ldmask = 0;
    {
        int gc = cbase + lane;
        bool cok = (lane < 34) && ((unsigned)gc < 512u);
        #pragma unroll
        for (int k = 0; k < 10; k++) {
            int gr = rbase + k;
            bool ok = cok && ((unsigned)gr < 512u);
            off[k] = ok ? (gr * 512 + gc) : 0;
            if (ok) ldmask |= 1u << k;
        }
    }

    const int owl = lane & 15;   // GEMM spatial mapping
    const int ohl = lane >> 4;

    float xr[10];
    float acc[32];
    #pragma unroll
    for (int i = 0; i < 32; i++) acc[i] = 0.f;

    // ---- pipeline helpers (manually inlined as macros via lambdas) ----
    auto prefetch = [&](int c0) {
        const float* xb = x + ((size_t)(n * 128 + c0 + wv)) * 262144;
        #pragma unroll
        for (int k = 0; k < 10; k++)
            xr[k] = ((ldmask >> k) & 1u) ? xb[off[k]] : 0.f;
    };
    auto vwrite = [&](int buf) {
        if (lane < 34) {
            #pragma unroll
            for (int o = 0; o < 4; o++) {
                float v = 0.125f * (xr[2 * o] + xr[2 * o + 3])
                        + 0.375f * (xr[2 * o + 1] + xr[2 * o + 2]);
                v_s[((buf * 8 + wv) * 4 + o) * VS + lane] = v;
            }
        }
    };

    prefetch(0);
    vwrite(0);
    prefetch(8);
    __syncthreads();

    for (int t = 0; t < 16; t++) {
        const int buf = t & 1;
        if (t < 15) {
            vwrite(buf ^ 1);                  // chunk t+1 -> other buffer
            if (t < 14) prefetch((t + 2) * 8); // issue loads for chunk t+2
        }
        // ---- GEMM over the 8 channels of chunk t ----
        #pragma unroll
        for (int cc = 0; cc < 8; cc++) {
            const float* vp = &v_s[((buf * 8 + cc) * 4 + ohl) * VS + 2 * owl];
            float v0 = vp[0], v1 = vp[1], v2 = vp[2], v3 = vp[3];
            float y = 0.125f * (v0 + v3) + 0.375f * (v1 + v2);
            const float* wrow = w + ((t * 8 + cc) << 8) + oc0;  // wave-uniform -> s_load
            #pragma unroll
            for (int i = 0; i < 32; i++)
                acc[i] = fmaf(wrow[i], y, acc[i]);
        }
        __syncthreads();   // v-writes(t+1) visible; GEMM(t) reads drained
    }

    // ---- epilogue: oc = oc0+i, oh = oh0+ohl, ow = ow0+owl ----
    {
        size_t base = (((size_t)n * 256 + oc0) * 256 + (size_t)(oh0 + ohl)) * 256
                      + ow0 + owl;
        #pragma unroll
        for (int i = 0; i < 32; i++)
            out[base + (size_t)i * 65536] = acc[i];
    }
}

extern "C" void kernel_launch(void* const* d_in, const int* in_sizes, int n_in,
                              void* d_out, int out_size, void* d_ws, size_t ws_size,
                              hipStream_t stream) {
    const float* x = (const float*)d_in[0];
    const float* w = (const float*)d_in[1];
    float* out = (float*)d_out;

    dim3 grid(16, 64, 4);   // ow-tiles(16 wide), oh-tiles(4 tall), n
    dim3 block(512);
    hipLaunchKernelGGL(fused_downconv_v7, grid, block, 0, stream, x, w, out);
}